// Round 2
// 862.891 us; speedup vs baseline: 1.2690x; 1.2690x over previous
//
#include <hip/hip_runtime.h>
#include <hip/hip_bf16.h>

typedef unsigned short u16;
typedef unsigned int u32x4 __attribute__((ext_vector_type(4)));
typedef __bf16 bf16x8 __attribute__((ext_vector_type(8)));
typedef float f32x4 __attribute__((ext_vector_type(4)));

__device__ __forceinline__ float b2f(u16 u) {
  union { unsigned int i; float f; } v; v.i = ((unsigned int)u) << 16; return v.f;
}
__device__ __forceinline__ u16 f2b(float f) {
  unsigned int x = __builtin_bit_cast(unsigned int, f);
  unsigned int r = (x + 0x7fffu + ((x >> 16) & 1u)) >> 16;
  return (u16)r;
}

// async global->LDS, 16B per lane; LDS dest is wave-uniform base, HW writes
// lane i's 16B at base + i*16 (m104/m108). Global source is per-lane.
__device__ __forceinline__ void stage16(const u16* g, u16* l) {
  __builtin_amdgcn_global_load_lds((const __attribute__((address_space(1))) void*)g,
                                   (__attribute__((address_space(3))) void*)l,
                                   16, 0, 0);
}

// ---------------- fp32 -> bf16 bulk convert --------------------------------
__global__ void cvt_k(const float* __restrict__ in, u16* __restrict__ out, long n) {
  long i = ((long)blockIdx.x * 256 + threadIdx.x) * 4;
  if (i + 3 < n) {
    float4 v = *(const float4*)(in + i);
    out[i] = f2b(v.x); out[i+1] = f2b(v.y); out[i+2] = f2b(v.z); out[i+3] = f2b(v.w);
  } else {
    for (long k = i; k < n; ++k) out[k] = f2b(in[k]);
  }
}

// ---- batched transpose + fp32->bf16: in [z][R,C] f32 -> out [z*ozs + C,ldo]
// rows R..ldo-1 of each output slab are ZERO-FILLED so GEMM K can be padded
// to a multiple of 32.
__global__ void transpose_k(const float* __restrict__ in, u16* __restrict__ out,
                            int R, int C, int ldo, long ozstride) {
  __shared__ float t[32][33];
  long ibase = (long)blockIdx.z * (long)R * C;
  long obase = (long)blockIdx.z * ozstride;
  int c0 = blockIdx.x * 32, r0 = blockIdx.y * 32;
  for (int i = threadIdx.y; i < 32; i += 8) {
    int r = r0 + i, c = c0 + threadIdx.x;
    t[i][threadIdx.x] = (r < R && c < C) ? in[ibase + (long)r * C + c] : 0.f;
  }
  __syncthreads();
  for (int i = threadIdx.y; i < 32; i += 8) {
    int c = c0 + i, r = r0 + threadIdx.x;
    if (c < C && r < ldo) out[obase + (long)c * ldo + r] = f2b(t[threadIdx.x][i]);
  }
}

// ---------------- column sums of block-diag weight [8,256,256] fp32 --------
__global__ void colsum_k(const float* __restrict__ W, float* __restrict__ out) {
  int h = blockIdx.x, o = threadIdx.x;
  const float* p = W + (long)h * 65536 + o;
  float s = 0.f;
  for (int i = 0; i < 256; ++i) s += p[i * 256];
  out[h * 256 + o] = s;
}

// ---------------- LayerNorm + causal-conv scalar + silu --> xc[B] ----------
__global__ void ln_conv_k(const float* __restrict__ x, const float* __restrict__ g,
                          const float* __restrict__ bb, const float* __restrict__ ck,
                          const float* __restrict__ cb, float* __restrict__ xc) {
  __shared__ float s1[4], s2[4];
  int b = blockIdx.x, tid = threadIdx.x;
  const float* xr = x + (long)b * 2048;
  float v[8], sum = 0.f, sq = 0.f;
  #pragma unroll
  for (int i = 0; i < 8; ++i) {
    float f = xr[tid + i * 256];
    v[i] = f; sum += f; sq += f * f;
  }
  #pragma unroll
  for (int off = 32; off; off >>= 1) {
    sum += __shfl_down(sum, off, 64);
    sq  += __shfl_down(sq,  off, 64);
  }
  int lane = tid & 63, wv = tid >> 6;
  if (!lane) { s1[wv] = sum; s2[wv] = sq; }
  __syncthreads();
  float tsum = s1[0] + s1[1] + s1[2] + s1[3];
  float tsq  = s2[0] + s2[1] + s2[2] + s2[3];
  float m = tsum * (1.f / 2048.f);
  float var = tsq * (1.f / 2048.f) - m * m;
  float rstd = rsqrtf(var + 1e-3f);
  float dot = 0.f;
  #pragma unroll
  for (int i = 0; i < 8; ++i) {
    int d = tid + i * 256;
    float xn = (v[i] - m) * rstd * g[d] + bb[d];
    dot += xn * ck[3 * 2048 + d];
  }
  #pragma unroll
  for (int off = 32; off; off >>= 1) dot += __shfl_down(dot, off, 64);
  __syncthreads();
  if (!lane) s1[wv] = dot;
  __syncthreads();
  if (tid == 0) {
    float s = s1[0] + s1[1] + s1[2] + s1[3] + cb[0];
    xc[b] = s / (1.f + expf(-s));  // silu
  }
}

// ---------------- MFMA GEMM: C = A1*B1t^T + A2*B2t^T (+bias)(+res) ---------
// m97 structure: 128x128 tile, BK=32, linear LDS [128][32], global_load_lds
// width 16. K1 and K1+K2 MUST be multiples of 32 (down-proj K padded
// 2730->2752=86*32, zeros on both operands).
// Epilogue col-split: for col >= nsplit the element offset gets += off2
// (used to scatter fused-N outputs into two adjacent logical buffers).
template<bool F32OUT>
__global__ __launch_bounds__(256) void gemm_bt(
    const u16* __restrict__ A1, long lda1, long sA1,
    const u16* __restrict__ Bt1, long ldb1, long sB1,
    const u16* __restrict__ A2, long lda2, long sA2,
    const u16* __restrict__ Bt2, long ldb2, long sB2,
    int K1, int K2,
    const float* __restrict__ bias,
    const float* __restrict__ res, long ldres,
    void* __restrict__ Cv, long ldc, long sC,
    int M, int N, int nsplit, long off2)
{
  __shared__ u16 As[128][32];
  __shared__ u16 Bs[128][32];
  const int bz = blockIdx.z;
  A1 += (long)bz * sA1; Bt1 += (long)bz * sB1;
  if (A2) { A2 += (long)bz * sA2; Bt2 += (long)bz * sB2; }
  const int m0 = blockIdx.y * 128, n0 = blockIdx.x * 128;
  const int tid = threadIdx.x;
  const int w = tid >> 6, lane = tid & 63;
  const int lr = lane & 15, quad = lane >> 4;
  const int wrow = (w & 1) * 64, wcol = (w >> 1) * 64;
  // staging geometry: wave w, chunk c -> 16 rows starting at (w*2+c)*16.
  // lane l covers row +l/4, elems [(l&3)*8, +8) == LDS base + l*16B (linear).
  const int srow = lane >> 2;        // 0..15
  const int scol = (lane & 3) * 8;   // element offset within BK=32
  f32x4 acc[4][4] = {};
  const int KT = K1 + K2;
  for (int kk = 0; kk < KT; kk += 32) {
    const u16 *PA, *PB; long lA, lB; int ko;
    if (kk < K1) { PA = A1; lA = lda1; PB = Bt1; lB = ldb1; ko = kk; }
    else         { PA = A2; lA = lda2; PB = Bt2; lB = ldb2; ko = kk - K1; }
    #pragma unroll
    for (int c = 0; c < 2; ++c) {
      const int r0 = (w * 2 + c) * 16;
      long ar = m0 + r0 + srow; if (ar > (long)M - 1) ar = M - 1;
      long br = n0 + r0 + srow; if (br > (long)N - 1) br = N - 1;  // OOB cols never stored
      stage16(PA + ar * lA + ko + scol, &As[r0][0]);
      stage16(PB + br * lB + ko + scol, &Bs[r0][0]);
    }
    asm volatile("s_waitcnt vmcnt(0)" ::: "memory");  // LDS-DMA drain (defensive)
    __syncthreads();
    bf16x8 af[4], bfr[4];
    #pragma unroll
    for (int i = 0; i < 4; ++i)
      af[i] = __builtin_bit_cast(bf16x8, *(const u32x4*)&As[wrow + i * 16 + lr][quad * 8]);
    #pragma unroll
    for (int j = 0; j < 4; ++j)
      bfr[j] = __builtin_bit_cast(bf16x8, *(const u32x4*)&Bs[wcol + j * 16 + lr][quad * 8]);
    #pragma unroll
    for (int i = 0; i < 4; ++i)
      #pragma unroll
      for (int j = 0; j < 4; ++j)
        acc[i][j] = __builtin_amdgcn_mfma_f32_16x16x32_bf16(af[i], bfr[j], acc[i][j], 0, 0, 0);
    __syncthreads();
  }
  #pragma unroll
  for (int i = 0; i < 4; ++i) {
    #pragma unroll
    for (int r = 0; r < 4; ++r) {
      int row = m0 + wrow + i * 16 + quad * 4 + r;
      if (row >= M) continue;
      #pragma unroll
      for (int j = 0; j < 4; ++j) {
        int col = n0 + wcol + j * 16 + lr;
        if (col >= N) continue;
        float v = acc[i][j][r];
        if (bias) v += bias[col];
        if (res)  v += res[(long)row * ldres + col];
        long e = (long)bz * sC + (long)row * ldc + col;
        if (col >= nsplit) e += off2;
        if (F32OUT) ((float*)Cv)[e] = v;
        else        ((u16*)Cv)[e] = f2b(v);
      }
    }
  }
}

// ---------------- gate elementwise math ------------------------------------
__global__ void gates_k(
    const u16* __restrict__ zpre, const u16* __restrict__ opre,
    const u16* __restrict__ ri,   const u16* __restrict__ rf,
    const float* __restrict__ xc, const float* __restrict__ csi, const float* __restrict__ csf,
    const float* __restrict__ Wz_b, const float* __restrict__ Rz_b,
    const float* __restrict__ Wi_b, const float* __restrict__ Ri_b,
    const float* __restrict__ Wf_b, const float* __restrict__ Rf_b,
    const float* __restrict__ Wo_b, const float* __restrict__ Ro_b,
    const float* __restrict__ c_prev, const float* __restrict__ n_prev, const float* __restrict__ m_prev,
    float* __restrict__ h_out, float* __restrict__ c_out,
    float* __restrict__ n_out, float* __restrict__ m_out)
{
  long idx = (long)blockIdx.x * 256 + threadIdx.x;
  int j = (int)(idx & 2047); long b = idx >> 11;
  float zp = b2f(zpre[idx]) + Wz_b[j] + Rz_b[j];
  float op = b2f(opre[idx]) + Wo_b[j] + Ro_b[j];
  float xcb = xc[b];
  float it = xcb * csi[j] + Wi_b[j] + b2f(ri[idx]) + Ri_b[j];
  float ft = xcb * csf[j] + Wf_b[j] + b2f(rf[idx]) + Rf_b[j];
  float z = tanhf(zp);
  float o = 1.f / (1.f + expf(-op));
  float mp = m_prev[idx];
  float mt = fmaxf(ft + mp, it);
  float ii = expf(it - mt), ff = expf(ft + mp - mt);
  float ct = ff * c_prev[idx] + ii * z;
  float nt = ff * n_prev[idx] + ii;
  float ht = o * ct / nt;
  h_out[idx] = ht; c_out[idx] = ct;
  n_out[idx] = nt; m_out[idx] = mt;
}

// ---------------- GroupNorm (8 groups of 256); h fp32 -> onorm bf16 --------
__global__ void groupnorm_k(const float* __restrict__ h, const float* __restrict__ gg,
                            const float* __restrict__ gb, u16* __restrict__ onorm) {
  int bg = blockIdx.x; int b = bg >> 3, g = bg & 7;
  long base = (long)b * 2048 + g * 256;
  int lane = threadIdx.x;
  float v[4], sum = 0.f, sq = 0.f;
  #pragma unroll
  for (int i = 0; i < 4; ++i) {
    float f = h[base + lane * 4 + i];
    v[i] = f; sum += f; sq += f * f;
  }
  #pragma unroll
  for (int off = 32; off; off >>= 1) {
    sum += __shfl_down(sum, off, 64);
    sq  += __shfl_down(sq,  off, 64);
  }
  sum = __shfl(sum, 0, 64); sq = __shfl(sq, 0, 64);
  float m = sum * (1.f / 256.f);
  float var = sq * (1.f / 256.f) - m * m;
  float rstd = rsqrtf(var + 1e-3f);
  #pragma unroll
  for (int i = 0; i < 4; ++i) {
    int j = g * 256 + lane * 4 + i;
    onorm[base + lane * 4 + i] = f2b((v[i] - m) * rstd * gg[j] + gb[j]);
  }
}

// -------- GLU combine on fused buf [4096][5504]: left=cols 0..2735,
// right=cols 2752..: act = (L+lb) * gelu_exact(R+rb); zero-fill 2730..2751
// (down-proj K padding).
__global__ void combine_k(u16* __restrict__ buf,
                          const float* __restrict__ lb, const float* __restrict__ rb) {
  int col = blockIdx.x * 256 + threadIdx.x;
  if (col >= 2752) return;
  long base = (long)blockIdx.y * 5504;
  if (col >= 2730) { buf[base + col] = 0; return; }
  float l = b2f(buf[base + col]) + lb[col];
  float r = b2f(buf[base + 2752 + col]) + rb[col];
  float gel = 0.5f * r * (1.f + erff(r * 0.70710678118654752f));
  buf[base + col] = f2b(l * gel);
}

extern "C" void kernel_launch(void* const* d_in, const int* in_sizes, int n_in,
                              void* d_out, int out_size, void* d_ws, size_t ws_size,
                              hipStream_t stream)
{
  const float* x      = (const float*)d_in[0];
  const float* h_prev = (const float*)d_in[1];
  const float* c_prev = (const float*)d_in[2];
  const float* n_prev = (const float*)d_in[3];
  const float* m_prev = (const float*)d_in[4];
  const float* ln_g   = (const float*)d_in[5];
  const float* ln_b   = (const float*)d_in[6];
  const float* conv_k = (const float*)d_in[7];
  const float* conv_b = (const float*)d_in[8];
  const float* Wz_w = (const float*)d_in[9];  const float* Wz_b = (const float*)d_in[10];
  const float* Wi_w = (const float*)d_in[11]; const float* Wi_b = (const float*)d_in[12];
  const float* Wf_w = (const float*)d_in[13]; const float* Wf_b = (const float*)d_in[14];
  const float* Wo_w = (const float*)d_in[15]; const float* Wo_b = (const float*)d_in[16];
  const float* Rz_w = (const float*)d_in[17]; const float* Rz_b = (const float*)d_in[18];
  const float* Ri_w = (const float*)d_in[19]; const float* Ri_b = (const float*)d_in[20];
  const float* Rf_w = (const float*)d_in[21]; const float* Rf_b = (const float*)d_in[22];
  const float* Ro_w = (const float*)d_in[23]; const float* Ro_b = (const float*)d_in[24];
  const float* gn_g = (const float*)d_in[25]; const float* gn_b = (const float*)d_in[26];
  const float* upL_w = (const float*)d_in[27]; const float* upL_b = (const float*)d_in[28];
  const float* upR_w = (const float*)d_in[29]; const float* upR_b = (const float*)d_in[30];
  const float* down_w = (const float*)d_in[31]; const float* down_b = (const float*)d_in[32];

  char* ws = (char*)d_ws;
  // ws layout (bytes)
  u16* zoW   = (u16*)(ws + 0);                // [8][512][256]  rows: Wz^T | Wo^T
  u16* zoR   = (u16*)(ws + 2097152);          // [8][512][256]  rows: Rz^T | Ro^T
  u16* irfW  = (u16*)(ws + 4194304);          // [8][512][256]  rows: Ri^T | Rf^T
  u16* upLT  = (u16*)(ws + 6291456);          // [5460][2048]  (upL^T | upR^T contiguous)
  u16* downT = (u16*)(ws + 28655616);         // [2048][2752]  rows 2730..2751 zero
  float* csi = (float*)(ws + 39945216);
  float* csf = (float*)(ws + 39953408);
  float* xc  = (float*)(ws + 39961600);
  u16* zpre  = (u16*)(ws + 39978000 + 2032);  // align: see below
  // NOTE: keep zpre 16B aligned; recompute fixed offsets:
  zpre  = (u16*)(ws + 39980032);              // [4096][2048] bf16
  u16* opre  = (u16*)(ws + 56757248);         // zpre + 16777216 B (8388608 elems)
  u16* ri    = (u16*)(ws + 73534464);
  u16* rf    = (u16*)(ws + 90311680);         // ri + 16777216 B
  u16* xb    = (u16*)(ws + 107088896);        // bf16(x) [4096][2048]
  u16* hb    = (u16*)(ws + 123866112);        // bf16(h_prev)
  // aliases (consumed-before-overwrite):
  u16* onorm = xb;                            // after gate GEMMs + groupnorm
  u16* updub = zpre;                          // [4096][5504]: L | pad | R (45.1MB, fits over gate bufs)

  float* out   = (float*)d_out;
  float* final_o = out;
  float* hout  = out + 8388608;
  float* cout  = out + 16777216;
  float* nout  = out + 25165824;
  float* mout  = out + 33554432;

  const long GATE_OFF2 = 8388608 - 256;   // col>=256 -> lands in next [4096][2048] slab
  const int  NOSPLIT = 1 << 30;

  dim3 tb(32, 8);
  // input conversions
  cvt_k<<<8192, 256, 0, stream>>>(x, xb, 8388608);
  cvt_k<<<8192, 256, 0, stream>>>(h_prev, hb, 8388608);
  // weight transposes (+bf16), interleaved per-head layouts for fused gates
  transpose_k<<<dim3(8, 8, 8), tb, 0, stream>>>(Wz_w, zoW,          256, 256, 256, 131072);
  transpose_k<<<dim3(8, 8, 8), tb, 0, stream>>>(Wo_w, zoW + 65536,  256, 256, 256, 131072);
  transpose_k<<<dim3(8, 8, 8), tb, 0, stream>>>(Rz_w, zoR,          256, 256, 256, 131072);
  transpose_k<<<dim3(8, 8, 8), tb, 0, stream>>>(Ro_w, zoR + 65536,  256, 256, 256, 131072);
  transpose_k<<<dim3(8, 8, 8), tb, 0, stream>>>(Ri_w, irfW,         256, 256, 256, 131072);
  transpose_k<<<dim3(8, 8, 8), tb, 0, stream>>>(Rf_w, irfW + 65536, 256, 256, 256, 131072);
  transpose_k<<<dim3(86, 64, 1), tb, 0, stream>>>(upL_w, upLT, 2048, 2730, 2048, 0);
  transpose_k<<<dim3(86, 64, 1), tb, 0, stream>>>(upR_w, upLT + (long)2730 * 2048, 2048, 2730, 2048, 0);
  transpose_k<<<dim3(64, 86, 1), tb, 0, stream>>>(down_w, downT, 2730, 2048, 2752, 0);
  // colsums for the rank-1 x_conv path
  colsum_k<<<8, 256, 0, stream>>>(Wi_w, csi);
  colsum_k<<<8, 256, 0, stream>>>(Wf_w, csf);
  // LN + conv scalar + silu
  ln_conv_k<<<4096, 256, 0, stream>>>(x, ln_g, ln_b, conv_k, conv_b, xc);
  // fused z+o gate GEMM: [xb|hb] @ [zoW;zoR]^T per head -> zpre / opre
  gemm_bt<false><<<dim3(4, 32, 8), 256, 0, stream>>>(
      xb, 2048, 256, zoW, 256, 131072, hb, 2048, 256, zoR, 256, 131072,
      256, 256, nullptr, nullptr, 0, zpre, 2048, 256, 4096, 512, 256, GATE_OFF2);
  // fused i+f recurrent GEMM: hb @ [Ri;Rf]^T per head -> ri / rf
  gemm_bt<false><<<dim3(4, 32, 8), 256, 0, stream>>>(
      hb, 2048, 256, irfW, 256, 131072, nullptr, 0, 0, nullptr, 0, 0,
      256, 0, nullptr, nullptr, 0, ri, 2048, 256, 4096, 512, 256, GATE_OFF2);
  // gate math -> h_t, c_t, n_t, m_t (fp32 outputs)
  gates_k<<<32768, 256, 0, stream>>>(zpre, opre, ri, rf, xc, csi, csf,
      Wz_b, Rz_b, Wi_b, Ri_b, Wf_b, Rf_b, Wo_b, Ro_b,
      c_prev, n_prev, m_prev, hout, cout, nout, mout);
  // GroupNorm (fp32 in from d_out, bf16 out)
  groupnorm_k<<<32768, 64, 0, stream>>>(hout, gn_g, gn_b, onorm);
  // fused up projection: onorm @ [upL|upR]^T, N=5460 -> updub halves
  gemm_bt<false><<<dim3(43, 32, 1), 256, 0, stream>>>(
      onorm, 2048, 0, upLT, 2048, 0, nullptr, 0, 0, nullptr, 0, 0,
      2048, 0, nullptr, nullptr, 0, updub, 5504, 0, 4096, 5460, 2730, 22);
  // GLU combine in place (left half), zero-pads K to 2752
  combine_k<<<dim3(11, 4096), 256, 0, stream>>>(updub, upL_b, upR_b);
  // down projection + bias + residual -> final output (fp32), K=2752
  gemm_bt<true><<<dim3(16, 32, 1), 256, 0, stream>>>(
      updub, 5504, 0, downT, 2752, 0, nullptr, 0, 0, nullptr, 0, 0,
      2752, 0, down_b, x, 2048, final_o, 2048, 0, 4096, 2048, NOSPLIT, 0);
}